// Round 3
// baseline (177.161 us; speedup 1.0000x reference)
//
#include <hip/hip_runtime.h>
#include <hip/hip_bf16.h>
#include <math.h>

// Problem constants: B=1, T=256, D=512, M=64, H=8, HD=64, IN=256, HID=256
#define T_ 256
#define D_ 512
#define M_ 64
#define H_ 8
#define HD_ 64
#define HID_ 256

typedef __attribute__((ext_vector_type(8))) short short8_t;
typedef __attribute__((ext_vector_type(4))) float f32x4;

union FragU { short8_t v; ushort4 q[2]; };

// float -> bf16 RTN-even
__device__ __forceinline__ ushort f2bf(float f) {
    union { float f; unsigned u; } x; x.f = f;
    unsigned r = x.u + 0x7FFF + ((x.u >> 16) & 1);
    return (ushort)(r >> 16);
}

// ---------------------------------------------------------------------------
// MFMA 64x64-tile GEMM engine (bf16 inputs via on-the-fly convert, fp32 acc).
// Block = 256 threads = 4 waves; wave w computes rows 16w..16w+15, cols 0..63
// of the block tile as 4 x (16x16) MFMA accumulators. K stepped by 32.
// A staged row-major bf16 [64][40]; B staged TRANSPOSED bf16 [n][k] [64][40].
// Frag k-mapping: k = 8*(lane>>4) + e for both A and B (any consistent
// bijection is correct since MFMA contracts over k).
// ---------------------------------------------------------------------------
__device__ __forceinline__ void mm_step(
    const float* __restrict__ A, int lda, int arow0, int ak0,
    const float* __restrict__ B, int ldb, int bk0, int bcol0,
    ushort (&As)[64][40], ushort (&Bs)[64][40], f32x4 (&acc)[4])
{
    const int tid = threadIdx.x;

    // stage A: 64 rows x 32 k
    #pragma unroll
    for (int i = 0; i < 2; ++i) {
        int f = tid + i * 256;            // float4 id 0..511
        int r = f >> 3, c4 = f & 7;       // row 0..63, k-group 0..7
        float4 v = *(const float4*)(A + (long)(arow0 + r) * lda + ak0 + c4 * 4);
        ushort4 hv;
        hv.x = f2bf(v.x); hv.y = f2bf(v.y); hv.z = f2bf(v.z); hv.w = f2bf(v.w);
        *(ushort4*)&As[r][c4 * 4] = hv;
    }
    // stage B transposed: 32 k x 64 n -> Bs[n][k]
    #pragma unroll
    for (int i = 0; i < 2; ++i) {
        int f = tid + i * 256;
        int kr = f >> 4, c4 = f & 15;     // k 0..31, col-group 0..15
        float4 v = *(const float4*)(B + (long)(bk0 + kr) * ldb + bcol0 + c4 * 4);
        Bs[c4 * 4 + 0][kr] = f2bf(v.x);
        Bs[c4 * 4 + 1][kr] = f2bf(v.y);
        Bs[c4 * 4 + 2][kr] = f2bf(v.z);
        Bs[c4 * 4 + 3][kr] = f2bf(v.w);
    }
    __syncthreads();

    const int w = tid >> 6;
    const int l = tid & 63;
    const int m = l & 15, g = l >> 4;

    FragU fa;
    fa.q[0] = *(const ushort4*)&As[16 * w + m][8 * g + 0];
    fa.q[1] = *(const ushort4*)&As[16 * w + m][8 * g + 4];
    #pragma unroll
    for (int c = 0; c < 4; ++c) {
        FragU fb;
        fb.q[0] = *(const ushort4*)&Bs[16 * c + m][8 * g + 0];
        fb.q[1] = *(const ushort4*)&Bs[16 * c + m][8 * g + 4];
        acc[c] = __builtin_amdgcn_mfma_f32_16x16x32_bf16(fa.v, fb.v, acc[c], 0, 0, 0);
    }
    __syncthreads();
}

template<bool ACT>
__device__ __forceinline__ void mm_write(
    float* __restrict__ C, int ldc, int row0, int col0,
    const float* __restrict__ bias, f32x4 (&acc)[4])
{
    const int tid = threadIdx.x;
    const int w = tid >> 6, l = tid & 63;
    const int m = l & 15, g = l >> 4;
    #pragma unroll
    for (int c = 0; c < 4; ++c) {
        int col = col0 + 16 * c + m;
        float bv = bias ? bias[col] : 0.f;
        #pragma unroll
        for (int r = 0; r < 4; ++r) {
            int row = row0 + 16 * w + 4 * g + r;
            float v = acc[c][r] + bv;
            if (ACT) v = v * __builtin_amdgcn_rcpf(1.f + __expf(-v));  // silu
            C[(long)row * ldc + col] = v;
        }
    }
}

// ---------------------------------------------------------------------------
// Fused QKV projection: y[z] = x @ W[z]. Grid (8, 4, 3).
// ---------------------------------------------------------------------------
__global__ __launch_bounds__(256) void qkv_kernel(
    const float* __restrict__ x,
    const float* __restrict__ Wq, const float* __restrict__ Wk,
    const float* __restrict__ Wv, float* __restrict__ y)
{
    __shared__ ushort As[64][40], Bs[64][40];
    const int z = blockIdx.z;
    const float* W = (z == 0) ? Wq : (z == 1) ? Wk : Wv;
    float* C = y + (long)z * (T_ * D_);
    const int row0 = blockIdx.y * 64, col0 = blockIdx.x * 64;

    f32x4 acc[4] = {};
    for (int k0 = 0; k0 < D_; k0 += 32)
        mm_step(x, D_, row0, k0, W, D_, k0, col0, As, Bs, acc);
    mm_write<false>(C, D_, row0, col0, nullptr, acc);
}

// ---------------------------------------------------------------------------
// Fused a_i / a_j with coords folded in via K-concatenation:
//   z = sel*8 + h :  abuf[z] = [ y[sel][:,h*64:+64] | coords ] @
//                              [ W1[sel*64:+64] ; W1[128+64*sel:+64] ]
//                              (+ b1 if sel==1)
// Grid (4, 4, 16). K = 64 + 64.
// ---------------------------------------------------------------------------
__global__ __launch_bounds__(256) void aiaj_kernel(
    const float* __restrict__ y, const float* __restrict__ coords,
    const float* __restrict__ W1, const float* __restrict__ b1,
    float* __restrict__ abuf)
{
    __shared__ ushort As[64][40], Bs[64][40];
    const int z = blockIdx.z;
    const int sel = z >> 3;      // 0 = a_i (q path), 1 = a_j (k path)
    const int h = z & 7;
    const float* Ay = y + (long)sel * (T_ * D_) + h * HD_;   // lda = 512
    const float* B1 = W1 + (long)sel * 64 * HID_;            // rows 0..63
    const float* B2 = W1 + (long)(128 + 64 * sel) * HID_;    // coords rows
    float* C = abuf + (long)z * (T_ * HID_);
    const int row0 = blockIdx.y * 64, col0 = blockIdx.x * 64;

    f32x4 acc[4] = {};
    mm_step(Ay, D_, row0, 0,  B1, HID_, 0,  col0, As, Bs, acc);
    mm_step(Ay, D_, row0, 32, B1, HID_, 32, col0, As, Bs, acc);
    mm_step(coords, M_, row0, 0,  B2, HID_, 0,  col0, As, Bs, acc);
    mm_step(coords, M_, row0, 32, B2, HID_, 32, col0, As, Bs, acc);
    mm_write<false>(C, HID_, row0, col0, (sel == 1) ? b1 : nullptr, acc);
}

// ---------------------------------------------------------------------------
// Generic epilogue GEMM: C = act(A @ B + bias). Grid (N/64, M/64).
// ---------------------------------------------------------------------------
template<bool ACT>
__global__ __launch_bounds__(256) void mm_kernel(
    const float* __restrict__ A, int lda,
    const float* __restrict__ B, int ldb,
    float* __restrict__ C, int ldc,
    const float* __restrict__ bias, int K)
{
    __shared__ ushort As[64][40], Bs[64][40];
    const int row0 = blockIdx.y * 64, col0 = blockIdx.x * 64;
    f32x4 acc[4] = {};
    for (int k0 = 0; k0 < K; k0 += 32)
        mm_step(A, lda, row0, k0, B, ldb, k0, col0, As, Bs, acc);
    mm_write<ACT>(C, ldc, row0, col0, bias, acc);
}

// ---------------------------------------------------------------------------
// Pairwise kernel v3: 32x32 (i,j) tile, 2x2 micro-tile, feature-chunked LDS
// (4 chunks of 64) for ~5 blocks/CU occupancy.
// linking[h,i,j] = tanh(0.5*(b2d + sum_f silu(ai+aj)*w2d))
// Grid (8 jt, 8 it, 8 h) = 512 blocks of 256 threads.
// ---------------------------------------------------------------------------
#define SILU_ACC(acc, w, aa, bb) \
    { float t_ = (aa) + (bb); \
      float sg_ = __builtin_amdgcn_rcpf(1.f + __expf(-t_)); \
      acc = fmaf((w) * t_, sg_, acc); }

__global__ __launch_bounds__(256) void pairwise_kernel(
    const float* __restrict__ a_i, const float* __restrict__ a_j,
    const float* __restrict__ W2, const float* __restrict__ b2,
    float* __restrict__ linking, float* __restrict__ partials)
{
    const int jt = blockIdx.x;
    const int it = blockIdx.y;
    const int h  = blockIdx.z;
    const int tid = threadIdx.x;

    __shared__ __align__(16) float ai_s[32][68];
    __shared__ __align__(16) float aj_s[32][68];
    __shared__ __align__(16) float w2d_s[256];
    __shared__ float red[256];

    w2d_s[tid] = W2[tid * 2 + 0] - W2[tid * 2 + 1];
    const float b2d = b2[0] - b2[1];

    const float* aib = a_i + ((long)h * T_ + it * 32) * HID_;
    const float* ajb = a_j + ((long)h * T_ + jt * 32) * HID_;

    const int ty = tid >> 4;   // 0..15
    const int tx = tid & 15;   // 0..15

    float s00 = 0.f, s01 = 0.f, s10 = 0.f, s11 = 0.f;

    for (int fc = 0; fc < 4; ++fc) {
        __syncthreads();   // protect LDS reuse (and w2d_s on first pass)
        #pragma unroll
        for (int i = 0; i < 2; ++i) {
            int f = tid + i * 256;          // float4 id 0..511
            int r = f >> 4, c4 = f & 15;    // row 0..31, col4 0..15
            *(float4*)&ai_s[r][c4 * 4] =
                *(const float4*)(aib + (long)r * HID_ + fc * 64 + c4 * 4);
            *(float4*)&aj_s[r][c4 * 4] =
                *(const float4*)(ajb + (long)r * HID_ + fc * 64 + c4 * 4);
        }
        __syncthreads();

        const float* wp = &w2d_s[fc * 64];
        #pragma unroll 4
        for (int f4 = 0; f4 < 16; ++f4) {
            float4 a0 = *(const float4*)&ai_s[ty][f4 * 4];
            float4 a1 = *(const float4*)&ai_s[ty + 16][f4 * 4];
            float4 c0 = *(const float4*)&aj_s[tx][f4 * 4];
            float4 c1 = *(const float4*)&aj_s[tx + 16][f4 * 4];
            float4 w  = *(const float4*)&wp[f4 * 4];
            SILU_ACC(s00, w.x, a0.x, c0.x); SILU_ACC(s01, w.x, a0.x, c1.x);
            SILU_ACC(s10, w.x, a1.x, c0.x); SILU_ACC(s11, w.x, a1.x, c1.x);
            SILU_ACC(s00, w.y, a0.y, c0.y); SILU_ACC(s01, w.y, a0.y, c1.y);
            SILU_ACC(s10, w.y, a1.y, c0.y); SILU_ACC(s11, w.y, a1.y, c1.y);
            SILU_ACC(s00, w.z, a0.z, c0.z); SILU_ACC(s01, w.z, a0.z, c1.z);
            SILU_ACC(s10, w.z, a1.z, c0.z); SILU_ACC(s11, w.z, a1.z, c1.z);
            SILU_ACC(s00, w.w, a0.w, c0.w); SILU_ACC(s01, w.w, a0.w, c1.w);
            SILU_ACC(s10, w.w, a1.w, c0.w); SILU_ACC(s11, w.w, a1.w, c1.w);
        }
    }

    float l00 = tanhf(0.5f * (s00 + b2d));
    float l01 = tanhf(0.5f * (s01 + b2d));
    float l10 = tanhf(0.5f * (s10 + b2d));
    float l11 = tanhf(0.5f * (s11 + b2d));

    float* lb = linking + ((long)h * T_) * T_;
    const int gi0 = it * 32 + ty, gi1 = gi0 + 16;
    const int gj0 = jt * 32 + tx, gj1 = gj0 + 16;
    lb[(long)gi0 * T_ + gj0] = l00;
    lb[(long)gi0 * T_ + gj1] = l01;
    lb[(long)gi1 * T_ + gj0] = l10;
    lb[(long)gi1 * T_ + gj1] = l11;

    float sum_l = l00 + l01 + l10 + l11;
    float sum_abs = fabsf(l00) + fabsf(l01) + fabsf(l10) + fabsf(l11);

    __syncthreads();
    red[tid] = sum_l;
    __syncthreads();
    for (int off = 128; off > 0; off >>= 1) {
        if (tid < off) red[tid] += red[tid + off];
        __syncthreads();
    }
    float tot_l = red[0];
    __syncthreads();
    red[tid] = sum_abs;
    __syncthreads();
    for (int off = 128; off > 0; off >>= 1) {
        if (tid < off) red[tid] += red[tid + off];
        __syncthreads();
    }
    if (tid == 0) {
        int slot = h * 64 + it * 8 + jt;
        partials[slot * 2 + 0] = tot_l;
        partials[slot * 2 + 1] = red[0];
    }
}

// ---------------------------------------------------------------------------
// Causal softmax + PV; block (0,0) also does the writhe/mean reduce.
// One 64-lane wave per (head, row).
// ---------------------------------------------------------------------------
__global__ __launch_bounds__(64) void attn_kernel(
    const float* __restrict__ linking, const float* __restrict__ yv,
    float* __restrict__ o, const float* __restrict__ partials,
    float* __restrict__ out_tail)
{
    const int i = blockIdx.x;
    const int h = blockIdx.y;
    const int lane = threadIdx.x;

    const float* lrow = linking + ((long)h * T_ + i) * T_;
    __shared__ float p[T_];

    float sv[4];
    float m = -1e30f;
    #pragma unroll
    for (int r = 0; r < 4; ++r) {
        int j = lane + r * 64;
        float s = (j <= i) ? lrow[j] * 0.125f : -1e30f;
        sv[r] = s;
        m = fmaxf(m, s);
    }
    for (int off = 32; off > 0; off >>= 1) m = fmaxf(m, __shfl_xor(m, off));

    float sum = 0.f;
    #pragma unroll
    for (int r = 0; r < 4; ++r) {
        int j = lane + r * 64;
        float e = (j <= i) ? __expf(sv[r] - m) : 0.f;
        p[j] = e;
        sum += e;
    }
    for (int off = 32; off > 0; off >>= 1) sum += __shfl_xor(sum, off);
    __syncthreads();

    const float inv = __builtin_amdgcn_rcpf(sum);
    const float* vb = yv + h * HD_ + lane;
    float a0 = 0.f, a1 = 0.f, a2 = 0.f, a3 = 0.f;
    int j = 0;
    for (; j + 3 <= i; j += 4) {
        a0 = fmaf(p[j + 0], vb[(long)(j + 0) * D_], a0);
        a1 = fmaf(p[j + 1], vb[(long)(j + 1) * D_], a1);
        a2 = fmaf(p[j + 2], vb[(long)(j + 2) * D_], a2);
        a3 = fmaf(p[j + 3], vb[(long)(j + 3) * D_], a3);
    }
    for (; j <= i; ++j) a0 = fmaf(p[j], vb[(long)j * D_], a0);
    o[(long)i * D_ + h * HD_ + lane] = ((a0 + a1) + (a2 + a3)) * inv;

    if (i == 0 && h == 0) {
        float a = 0.f;
        for (int e = lane; e < 512; e += 64) a += partials[e * 2 + 1];
        for (int off = 32; off > 0; off >>= 1) a += __shfl_xor(a, off);
        if (lane < 8) {
            float wsum = 0.f;
            for (int b = 0; b < 64; ++b) wsum += partials[(lane * 64 + b) * 2 + 0];
            out_tail[lane] = wsum;
        }
        if (lane == 0) out_tail[8] = a / (float)(H_ * T_ * T_);
    }
}

// ---------------------------------------------------------------------------
extern "C" void kernel_launch(void* const* d_in, const int* in_sizes, int n_in,
                              void* d_out, int out_size, void* d_ws, size_t ws_size,
                              hipStream_t stream)
{
    const float* x      = (const float*)d_in[0];
    const float* coords = (const float*)d_in[1];
    const float* Wq     = (const float*)d_in[2];
    const float* Wk     = (const float*)d_in[3];
    const float* Wv     = (const float*)d_in[4];
    const float* Wo     = (const float*)d_in[5];
    const float* W1     = (const float*)d_in[6];
    const float* b1     = (const float*)d_in[7];
    const float* W2     = (const float*)d_in[8];
    const float* b2     = (const float*)d_in[9];
    const float* W3     = (const float*)d_in[10];
    const float* b3     = (const float*)d_in[11];
    const float* W4     = (const float*)d_in[12];
    const float* b4     = (const float*)d_in[13];
    float* out = (float*)d_out;

    float* ws = (float*)d_ws;
    float* y    = ws;                    // 3 * 256*512
    float* abuf = ws + 393216;           // 16 * 256*256 (a_i 0..7 | a_j 8..15)
    float* lkb  = ws + 1441792;          // 8*256*256
    float* o    = ws + 1966080;          // 256*512
    float* g1   = ws + 2097152;
    float* g2   = ws + 2228224;
    float* parts= ws + 2359296;          // 512*2

    dim3 blk(256);

    // 1) q,k,v projections (MFMA)
    qkv_kernel<<<dim3(8, 4, 3), blk, 0, stream>>>(x, Wq, Wk, Wv, y);

    // 2) a_i / a_j with coords folded in (MFMA, K=128 concat)
    aiaj_kernel<<<dim3(4, 4, 16), blk, 0, stream>>>(y, coords, W1, b1, abuf);

    // 3) pairwise silu-MLP -> linking + partial sums
    pairwise_kernel<<<dim3(8, 8, 8), blk, 0, stream>>>(
        abuf, abuf + 8 * T_ * HID_, W2, b2, lkb, parts);

    // 4) causal softmax + PV (+ writhe/mean reduce in block (0,0))
    attn_kernel<<<dim3(T_, H_), dim3(64), 0, stream>>>(
        lkb, y + 2 * (T_ * D_), o, parts, out + 131072);

    // 5) epilogue: out = (silu(o@W3+b3) @ W4 + b4) @ Wo   (MFMA)
    mm_kernel<true ><<<dim3(8, 4), blk, 0, stream>>>(o,  D_, W3, D_, g1,  D_, b3, D_);
    mm_kernel<false><<<dim3(8, 4), blk, 0, stream>>>(g1, D_, W4, D_, g2,  D_, b4, D_);
    mm_kernel<false><<<dim3(8, 4), blk, 0, stream>>>(g2, D_, Wo, D_, out, D_, nullptr, D_);
}